// Round 9
// baseline (51.598 us; speedup 1.0000x reference)
//
#include <hip/hip_runtime.h>
#include <math.h>

#define BATCH     262144
#define NASSETS   128
#define TILE_ROWS 32                     // rows per K1 block (= one scan chunk)
#define NBLK      (BATCH / TILE_ROWS)    // 8192
#define SCHUNK    32                     // scan / replay chunk (rows)
#define NSC       (BATCH / SCHUNK)       // 8192 chunks
#define TBLK      128                    // k_tail blocks (1 wave each)
#define TCH       (NSC / TBLK)           // 64 chunks per tail block = 1/lane
#define ETA       0.01
#define CDECAY    0.99
#define EPS       1e-8
#define LPAD      33

__device__ __forceinline__ float dot4(float4 a, float4 b) {
  return a.x * b.x + a.y * b.y + a.z * b.z + a.w * b.w;
}

// base^e by square-multiply, e < 8192 (13 bits).
__device__ __forceinline__ double mpow(double base, int e) {
  double r = 1.0, p = base;
  #pragma unroll
  for (int b = 0; b < 13; ++b) { if (e & (1 << b)) r *= p; p *= p; }
  return r;
}

// K1: UNCHANGED structure from R7 (global_load_lds staging, 32-row tiles,
// 4 blocks/CU; measured ~97% of the 6.3 TB/s stream ceiling). Block 0
// zeroes the tail's finish counter.
__global__ __launch_bounds__(256) void k_rows(
    const float* __restrict__ W, const float* __restrict__ X,
    float* __restrict__ R, double* __restrict__ SA, double* __restrict__ SB,
    unsigned* __restrict__ cnt) {
  __shared__ float wbuf[TILE_ROWS * NASSETS];   // 16 KB
  __shared__ float xbuf[TILE_ROWS * NASSETS];   // 16 KB
  __shared__ float part[TILE_ROWS * LPAD];      // 4.2 KB
  __shared__ float hs[256];                     // 1 KB
  const int t   = threadIdx.x;
  const int blk = blockIdx.x;
  const int w   = t >> 6, l = t & 63;
  const float4* W4 = reinterpret_cast<const float4*>(W) + (size_t)blk * 1024;
  const float4* X4 = reinterpret_cast<const float4*>(X) + (size_t)blk * 1024;

  if (blk == 0 && t == 0) cnt[0] = 0u;

  // Stage: 32 x 1KB DMA instrs (16B/lane, linear LDS dest = base + lane*16).
  #pragma unroll
  for (int j = 0; j < 4; ++j) {
    const int seg = w * 4 + j;                  // 0..15 (256-float segment)
    const float4* gw = W4 + seg * 64 + l;
    const float4* gx = X4 + seg * 64 + l;
    __builtin_amdgcn_global_load_lds(
        (const __attribute__((address_space(1))) void*)gw,
        (__attribute__((address_space(3))) void*)&wbuf[seg * 256], 16, 0, 0);
    __builtin_amdgcn_global_load_lds(
        (const __attribute__((address_space(1))) void*)gx,
        (__attribute__((address_space(3))) void*)&xbuf[seg * 256], 16, 0, 0);
  }
  __syncthreads();                              // drains vmcnt (DMA complete)

  // Partial dots: contiguous ds_read_b128 (conflict-free), padded writes.
  #pragma unroll
  for (int p = 0; p < 4; ++p) {
    const int idx = p * 256 + t;
    const float4 a = reinterpret_cast<const float4*>(wbuf)[idx];
    const float4 b = reinterpret_cast<const float4*>(xbuf)[idx];
    part[(idx >> 5) * LPAD + (idx & 31)] = dot4(a, b);
  }
  __syncthreads();

  // Eighth-row sums (all 256 threads), then 32 threads finish + carry.
  {
    const int row = t & 31, q = t >> 5;         // q = 0..7, 4 cols each
    float s = 0.f;
    #pragma unroll
    for (int j = 0; j < 4; ++j) s += part[row * LPAD + q * 4 + j];
    hs[t] = s;
  }
  __syncthreads();
  if (t < TILE_ROWS) {
    float sum = 0.f;
    #pragma unroll
    for (int q = 0; q < 8; ++q) sum += hs[t + q * 32];
    R[(size_t)blk * TILE_ROWS + t] = sum;

    const int e = 31 - t;                   // wgt = ETA * c^e via square-select
    const double c1 = CDECAY, c2 = c1*c1, c4 = c2*c2, c8 = c4*c4, c16 = c8*c8;
    double wgt = ETA;
    if (e & 1)  wgt *= c1;
    if (e & 2)  wgt *= c2;
    if (e & 4)  wgt *= c4;
    if (e & 8)  wgt *= c8;
    if (e & 16) wgt *= c16;
    const double r = (double)sum;
    double sA = wgt * r, sB = wgt * r * r;
    sA += __shfl_xor(sA, 16, 64); sB += __shfl_xor(sB, 16, 64);
    sA += __shfl_xor(sA,  8, 64); sB += __shfl_xor(sB,  8, 64);
    sA += __shfl_xor(sA,  4, 64); sB += __shfl_xor(sB,  4, 64);
    sA += __shfl_xor(sA,  2, 64); sB += __shfl_xor(sB,  2, 64);
    sA += __shfl_xor(sA,  1, 64); sB += __shfl_xor(sB,  1, 64);
    if (t == 0) { SA[blk] = sA; SB[blk] = sB; }
  }
}

// K2 (k_tail): 128 independent blocks x 1 wave. Lane t owns chunk b*64+t —
// full-wave Hillis-Steele scan, no cross-wave combine. Incoming carry
// recomputed redundantly from the 256-chunk predecessor window (older terms
// carry c^8192 ~ 1.6e-36 -> dropped). Per-block partial store (distinct
// addresses, no same-address atomic convoy); last finisher reduces.
__global__ __launch_bounds__(64) void k_tail(
    const float* __restrict__ R, const double* __restrict__ SA,
    const double* __restrict__ SB, const float* __restrict__ A0p,
    const float* __restrict__ B0p, double* __restrict__ partial,
    unsigned* __restrict__ cnt, float* __restrict__ out) {
  __shared__ float lr[TCH * LPAD];      // 8.4 KB
  const int t = threadIdx.x;            // 0..63
  const int b = blockIdx.x;             // 0..127

  // Stage this block's 2048 R values (coalesced; both LDS patterns 2-way = free).
  const float* Rb = R + (size_t)b * (TCH * SCHUNK);
  #pragma unroll
  for (int q = 0; q < 32; ++q) {
    const int fi = q * 64 + t;          // row = fi>>5, col = fi&31
    lr[(fi >> 5) * LPAD + (fi & 31)] = Rb[fi];
  }

  double m = CDECAY;                    // -> c^32 (per-chunk factor)
  #pragma unroll
  for (int q = 0; q < 5; ++q) m = m * m;

  // Incoming carry from the 256-chunk predecessor window (4 chunks/lane).
  const int wbase = b * TCH - 256;
  double xA = 0.0, xB = 0.0;
  #pragma unroll
  for (int s = 0; s < 4; ++s) {
    const int j = t + s * 64;           // 0..255
    const int g = wbase + j;
    if (g >= 0) {
      const double wgt = mpow(m, 255 - j);
      xA += wgt * SA[g];
      xB += wgt * SB[g];
    }
  }
  #pragma unroll
  for (int d = 32; d >= 1; d >>= 1) {
    xA += __shfl_xor(xA, d, 64);
    xB += __shfl_xor(xB, d, 64);
  }

  // Own chunk + exclusive full-wave scan (factor m).
  const int c = b * TCH + t;
  double iA = SA[c], iB = SB[c], f = m;
  #pragma unroll
  for (int d = 1; d < 64; d <<= 1) {
    const double uA = __shfl_up(iA, d, 64);
    const double uB = __shfl_up(iB, d, 64);
    if (t >= d) { iA += f * uA; iB += f * uB; }
    f *= f;
  }
  double eA = __shfl_up(iA, 1, 64);
  double eB = __shfl_up(iB, 1, 64);
  if (t == 0) { eA = 0.0; eB = 0.0; }

  // State entering chunk c: local scan + decayed window carry + homog. term.
  const double mt  = mpow(m, t);
  const double hmg = mpow(m, c);
  double A = eA + xA * mt + (double)A0p[0] * hmg;
  double B = eB + xB * mt + (double)B0p[0] * hmg;
  __syncthreads();                      // lr staged (single wave: cheap)

  // Replay 32 rows: f64 recurrence + numerator, f32 rsqrt for var^-1.5.
  double sum = 0.0;
  #pragma unroll
  for (int k = 0; k < SCHUNK; ++k) {
    const double rv = (double)lr[t * LPAD + k];
    const double dA = ETA * (rv - A);
    const double dB = ETA * (rv * rv - B);
    double var = B - A * A;
    var = var > EPS ? var : EPS;
    const double num = B * dA - 0.5 * A * dB;
    const float inv = rsqrtf((float)var);
    sum += num * (double)(inv * inv * inv);
    A += dA;
    B += dB;
  }
  #pragma unroll
  for (int d = 32; d >= 1; d >>= 1) sum += __shfl_xor(sum, d, 64);

  unsigned old = 0u;
  if (t == 0) {
    partial[b] = sum;                   // distinct address per block
    __threadfence();                    // publish partial before counting
    old = atomicAdd(cnt, 1u);
  }
  old = __shfl(old, 0, 64);
  if (old == TBLK - 1) {
    // Last finisher: atomic loads (parallel latency, coherent) + reduce.
    double s2 = atomicAdd(&partial[t], 0.0) + atomicAdd(&partial[t + 64], 0.0);
    #pragma unroll
    for (int d = 32; d >= 1; d >>= 1) s2 += __shfl_xor(s2, d, 64);
    if (t == 0) out[0] = (float)(-s2 / (double)BATCH);
  }
}

extern "C" void kernel_launch(void* const* d_in, const int* in_sizes, int n_in,
                              void* d_out, int out_size, void* d_ws, size_t ws_size,
                              hipStream_t stream) {
  const float* W  = (const float*)d_in[0];
  const float* X  = (const float*)d_in[1];
  const float* A0 = (const float*)d_in[2];
  const float* B0 = (const float*)d_in[3];

  char* ws = (char*)d_ws;
  float*  R  = (float*)ws;                                 // 1 MB
  double* SA = (double*)(ws + (size_t)BATCH * 4);          // 64 KB
  double* SB = SA + NSC;                                   // 64 KB
  double* partial = SB + NSC;                              // 1 KB
  unsigned* cnt = (unsigned*)(partial + TBLK);             // 4 B

  k_rows<<<NBLK, 256, 0, stream>>>(W, X, R, SA, SB, cnt);
  k_tail<<<TBLK, 64, 0, stream>>>(R, SA, SB, A0, B0, partial, cnt, (float*)d_out);
}

// Round 10
// 50.572 us; speedup vs baseline: 1.0203x; 1.0203x over previous
//
#include <hip/hip_runtime.h>
#include <math.h>

#define BATCH     262144
#define NASSETS   128
#define TILE_ROWS 32                     // rows per K1 block (= one scan chunk)
#define NBLK      (BATCH / TILE_ROWS)    // 8192
#define SCHUNK    32                     // scan / replay chunk (rows)
#define NSC       (BATCH / SCHUNK)       // 8192 chunks
#define TBLK      64                     // k_tail blocks
#define TCH       (NSC / TBLK)           // 128 chunks per tail block
#define ETA       0.01
#define CDECAY    0.99
#define EPS       1e-8
#define LPAD      33

__device__ __forceinline__ float dot4(float4 a, float4 b) {
  return a.x * b.x + a.y * b.y + a.z * b.z + a.w * b.w;
}

// base^e by square-multiply, e < 8192 (13 bits).
__device__ __forceinline__ double mpow(double base, int e) {
  double r = 1.0, p = base;
  #pragma unroll
  for (int b = 0; b < 13; ++b) { if (e & (1 << b)) r *= p; p *= p; }
  return r;
}

// K1: global_load_lds staging, 32-row tiles, 4 blocks/CU — measured ~95% of
// the 6.3 TB/s stream ceiling (best known). Block 0 zeroes acc/cnt.
__global__ __launch_bounds__(256) void k_rows(
    const float* __restrict__ W, const float* __restrict__ X,
    float* __restrict__ R, double* __restrict__ SA, double* __restrict__ SB,
    double* __restrict__ acc, unsigned* __restrict__ cnt) {
  __shared__ float wbuf[TILE_ROWS * NASSETS];   // 16 KB
  __shared__ float xbuf[TILE_ROWS * NASSETS];   // 16 KB
  __shared__ float part[TILE_ROWS * LPAD];      // 4.2 KB
  __shared__ float hs[256];                     // 1 KB
  const int t   = threadIdx.x;
  const int blk = blockIdx.x;
  const int w   = t >> 6, l = t & 63;
  const float4* W4 = reinterpret_cast<const float4*>(W) + (size_t)blk * 1024;
  const float4* X4 = reinterpret_cast<const float4*>(X) + (size_t)blk * 1024;

  if (blk == 0 && t == 0) { acc[0] = 0.0; cnt[0] = 0u; }

  // Stage: 32 x 1KB DMA instrs (16B/lane, linear LDS dest = base + lane*16).
  #pragma unroll
  for (int j = 0; j < 4; ++j) {
    const int seg = w * 4 + j;                  // 0..15 (256-float segment)
    const float4* gw = W4 + seg * 64 + l;
    const float4* gx = X4 + seg * 64 + l;
    __builtin_amdgcn_global_load_lds(
        (const __attribute__((address_space(1))) void*)gw,
        (__attribute__((address_space(3))) void*)&wbuf[seg * 256], 16, 0, 0);
    __builtin_amdgcn_global_load_lds(
        (const __attribute__((address_space(1))) void*)gx,
        (__attribute__((address_space(3))) void*)&xbuf[seg * 256], 16, 0, 0);
  }
  __syncthreads();                              // drains vmcnt (DMA complete)

  // Partial dots: contiguous ds_read_b128 (conflict-free), padded writes.
  #pragma unroll
  for (int p = 0; p < 4; ++p) {
    const int idx = p * 256 + t;
    const float4 a = reinterpret_cast<const float4*>(wbuf)[idx];
    const float4 b = reinterpret_cast<const float4*>(xbuf)[idx];
    part[(idx >> 5) * LPAD + (idx & 31)] = dot4(a, b);
  }
  __syncthreads();

  // Eighth-row sums (all 256 threads), then 32 threads finish + carry.
  {
    const int row = t & 31, q = t >> 5;         // q = 0..7, 4 cols each
    float s = 0.f;
    #pragma unroll
    for (int j = 0; j < 4; ++j) s += part[row * LPAD + q * 4 + j];
    hs[t] = s;
  }
  __syncthreads();
  if (t < TILE_ROWS) {
    float sum = 0.f;
    #pragma unroll
    for (int q = 0; q < 8; ++q) sum += hs[t + q * 32];
    R[(size_t)blk * TILE_ROWS + t] = sum;

    const int e = 31 - t;                   // wgt = ETA * c^e via square-select
    const double c1 = CDECAY, c2 = c1*c1, c4 = c2*c2, c8 = c4*c4, c16 = c8*c8;
    double wgt = ETA;
    if (e & 1)  wgt *= c1;
    if (e & 2)  wgt *= c2;
    if (e & 4)  wgt *= c4;
    if (e & 8)  wgt *= c8;
    if (e & 16) wgt *= c16;
    const double r = (double)sum;
    double sA = wgt * r, sB = wgt * r * r;
    sA += __shfl_xor(sA, 16, 64); sB += __shfl_xor(sB, 16, 64);
    sA += __shfl_xor(sA,  8, 64); sB += __shfl_xor(sB,  8, 64);
    sA += __shfl_xor(sA,  4, 64); sB += __shfl_xor(sB,  4, 64);
    sA += __shfl_xor(sA,  2, 64); sB += __shfl_xor(sB,  2, 64);
    sA += __shfl_xor(sA,  1, 64); sB += __shfl_xor(sB,  1, 64);
    if (t == 0) { SA[blk] = sA; SB[blk] = sB; }
  }
}

// K2 (k_tail): 64 INDEPENDENT blocks x 128 threads (the R7-proven best).
// Incoming carry recomputed redundantly from the 256-chunk predecessor
// window (older terms carry c^8192 ~ 1.6e-36 -> dropped).
__global__ __launch_bounds__(128) void k_tail(
    const float* __restrict__ R, const double* __restrict__ SA,
    const double* __restrict__ SB, const float* __restrict__ A0p,
    const float* __restrict__ B0p, double* __restrict__ acc,
    unsigned* __restrict__ cnt, float* __restrict__ out) {
  __shared__ float  lr[TCH * LPAD];     // 16.9 KB
  __shared__ double wred[4];
  const int t = threadIdx.x;            // 0..127
  const int b = blockIdx.x;             // 0..63
  const int lane = t & 63, w = t >> 6;

  const float* Rb = R + (size_t)b * (TCH * SCHUNK);
  #pragma unroll
  for (int q = 0; q < 32; ++q) {
    const int fi = q * 128 + t;
    lr[(fi >> 5) * LPAD + (fi & 31)] = Rb[fi];
  }

  double m = CDECAY;                    // -> c^32 (per-chunk factor)
  #pragma unroll
  for (int q = 0; q < 5; ++q) m = m * m;

  // Incoming carry from the 256-chunk predecessor window.
  const int wbase = b * TCH - 256;
  double xA = 0.0, xB = 0.0;
  #pragma unroll
  for (int s = 0; s < 2; ++s) {
    const int j = t + s * 128;
    const int g = wbase + j;
    if (g >= 0) {
      const double wgt = mpow(m, 255 - j);
      xA += wgt * SA[g];
      xB += wgt * SB[g];
    }
  }
  #pragma unroll
  for (int d = 32; d >= 1; d >>= 1) {
    xA += __shfl_xor(xA, d, 64);
    xB += __shfl_xor(xB, d, 64);
  }
  if (lane == 0) { wred[w * 2] = xA; wred[w * 2 + 1] = xB; }
  __syncthreads();
  xA = wred[0] + wred[2];
  xB = wred[1] + wred[3];
  __syncthreads();

  // Own chunk values + exclusive scan (factor m) across the 128 chunks.
  const int c = b * TCH + t;
  double iA = SA[c], iB = SB[c], f = m;
  #pragma unroll
  for (int d = 1; d < 64; d <<= 1) {
    const double uA = __shfl_up(iA, d, 64);
    const double uB = __shfl_up(iB, d, 64);
    if (lane >= d) { iA += f * uA; iB += f * uB; }
    f *= f;
  }
  double eA = __shfl_up(iA, 1, 64);
  double eB = __shfl_up(iB, 1, 64);
  if (lane == 0) { eA = 0.0; eB = 0.0; }
  if (lane == 63) { wred[w * 2] = iA; wred[w * 2 + 1] = iB; }
  __syncthreads();
  const double mlane = mpow(m, lane);
  if (w == 1) { eA += wred[0] * mlane; eB += wred[1] * mlane; }

  const double mt  = mpow(m, t);
  const double hmg = mpow(m, b * TCH + t);
  double A = eA + xA * mt + (double)A0p[0] * hmg;
  double B = eB + xB * mt + (double)B0p[0] * hmg;

  double sum = 0.0;
  #pragma unroll
  for (int k = 0; k < SCHUNK; ++k) {
    const double rv = (double)lr[t * LPAD + k];
    const double dA = ETA * (rv - A);
    const double dB = ETA * (rv * rv - B);
    double var = B - A * A;
    var = var > EPS ? var : EPS;
    const double num = B * dA - 0.5 * A * dB;
    const float inv = rsqrtf((float)var);
    sum += num * (double)(inv * inv * inv);
    A += dA;
    B += dB;
  }
  #pragma unroll
  for (int d = 32; d >= 1; d >>= 1) sum += __shfl_xor(sum, d, 64);
  __syncthreads();
  if (lane == 0) wred[w] = sum;
  __syncthreads();
  if (t == 0) {
    atomicAdd(acc, wred[0] + wred[1]);
    __threadfence();
    const unsigned old = atomicAdd(cnt, 1u);
    if (old == TBLK - 1) {
      const double v = atomicAdd(acc, 0.0);
      out[0] = (float)(-v / (double)BATCH);
    }
  }
}

extern "C" void kernel_launch(void* const* d_in, const int* in_sizes, int n_in,
                              void* d_out, int out_size, void* d_ws, size_t ws_size,
                              hipStream_t stream) {
  const float* W  = (const float*)d_in[0];
  const float* X  = (const float*)d_in[1];
  const float* A0 = (const float*)d_in[2];
  const float* B0 = (const float*)d_in[3];

  char* ws = (char*)d_ws;
  float*  R  = (float*)ws;                                 // 1 MB
  double* SA = (double*)(ws + (size_t)BATCH * 4);          // 64 KB
  double* SB = SA + NSC;                                   // 64 KB
  double* acc = SB + NSC;                                  // 8 B
  unsigned* cnt = (unsigned*)(acc + 1);                    // 4 B

  k_rows<<<NBLK, 256, 0, stream>>>(W, X, R, SA, SB, acc, cnt);
  k_tail<<<TBLK, 128, 0, stream>>>(R, SA, SB, A0, B0, acc, cnt, (float*)d_out);
}